// Round 9
// baseline (137.667 us; speedup 1.0000x reference)
//
#include <hip/hip_runtime.h>
#include <hip/hip_bf16.h>
#include <cstdint>
#include <cstddef>

// SelfAttentionV2: x[4096,1024] fp32; Wq/Wk/Wv [1024,1024] fp32.
// out = softmax(causal((x Wq^T)(x Wk^T)^T / 32)) @ (x Wv^T), fp32 out.
//
// GEMM structure: 256(M)x128(N) tile, 8 waves (512 thr, 4Mx2N), per-wave out
// 64x64 (acc[4][4]), BK=32, 3 LDS K-tile ring buffers (72KB -> 2 blocks/CU).
// ONE barrier per K-tile (R8-verified schedule, re-counted for 3 loads/tile):
//   { 8 ds_read (a[4],b[4]) | 3 global_load_lds for tile s+2 into buf(s+2)%3
//     -> lgkmcnt(0) -> vmcnt(3) -> s_barrier -> setprio(1) 16 MFMA setprio(0) }
// Hazard proof: before barrier(s) every wave drained its own ds_reads and
// tile s+1's stages landed (vmcnt(3): 6 outstanding - 3 just issued). Stage
// at s targets buf(s+2)%3 = buffer read at s-1, whose reads completed before
// barrier(s-1). Grids are all >=256 blocks (qkv 384 / qkt 272 / pv 320) at
// 2 blocks/CU — full CU coverage + cross-block latency hiding.
// LDS rows 64B; XOR swizzle byte ^= ((byte>>9)&1)<<5 applied to the global
// SOURCE on stage (global_load_lds writes linearly) and to ds_read addrs.

#define SEQQ 4096
#define DDIM 1024

typedef __bf16 bf16x8 __attribute__((ext_vector_type(8)));
typedef float f32x4 __attribute__((ext_vector_type(4)));

__device__ __forceinline__ unsigned short f2bf(float f) {
  unsigned int u = __builtin_bit_cast(unsigned int, f);
  unsigned int r = u + 0x7FFFu + ((u >> 16) & 1u);  // RNE; -inf stays -inf
  return (unsigned short)(r >> 16);
}

__device__ __forceinline__ void gload_lds16(const void* g, void* lds) {
  __builtin_amdgcn_global_load_lds(
      (__attribute__((address_space(1))) void*)(uintptr_t)g,
      (__attribute__((address_space(3))) void*)(uintptr_t)lds, 16, 0, 0);
}

// ---- fused fp32 -> bf16 conversion (x, Wq*1/32, Wk, Wv) ----
__global__ __launch_bounds__(256) void cvt_all(const float* __restrict__ x,
                                               const float* __restrict__ Wq,
                                               const float* __restrict__ Wk,
                                               const float* __restrict__ Wv,
                                               unsigned short* __restrict__ xb,
                                               unsigned short* __restrict__ Wcat) {
  int b = blockIdx.x;
  const float* src;
  unsigned short* dst;
  float scale = 1.0f;
  if (b < 4096) {
    src = x; dst = xb;
  } else if (b < 5120) {
    src = Wq; dst = Wcat; scale = 0.03125f; b -= 4096;
  } else if (b < 6144) {
    src = Wk; dst = Wcat + (1u << 20); b -= 5120;
  } else {
    src = Wv; dst = Wcat + (2u << 20); b -= 6144;
  }
  const int i = (b * 256 + threadIdx.x) * 4;
  const float4 v = *reinterpret_cast<const float4*>(src + i);
  ushort4 o;
  o.x = f2bf(v.x * scale);
  o.y = f2bf(v.y * scale);
  o.z = f2bf(v.z * scale);
  o.w = f2bf(v.w * scale);
  *reinterpret_cast<ushort4*>(dst + i) = o;
}

// ---- 256x128 GEMM core: LDS A[3][256r][32c], B[3][128r][32c] bf16 ----
#define GEMM_PRE()                                                          \
  __shared__ unsigned short As[3][8192] __attribute__((aligned(16)));       \
  __shared__ unsigned short Bs[3][4096] __attribute__((aligned(16)));       \
  const int tid = threadIdx.x;                                              \
  const int wave = tid >> 6, lane = tid & 63;                               \
  const int wr = (wave >> 1) * 64, wc = (wave & 1) * 64;                    \
  f32x4 acc[4][4] = {};                                                     \
  int offA[4], offB[4];                                                     \
  {                                                                         \
    const int cb = (lane >> 4) * 16;                                        \
    const int rA = wr + (lane & 15);                                        \
    _Pragma("unroll")                                                       \
    for (int m = 0; m < 4; ++m) {                                           \
      int o = (rA + m * 16) * 64 + cb;                                      \
      offA[m] = o ^ (((o >> 9) & 1) << 5);                                  \
    }                                                                       \
    const int rB = wc + (lane & 15);                                        \
    _Pragma("unroll")                                                       \
    for (int n = 0; n < 4; ++n) {                                           \
      int o = (rB + n * 16) * 64 + cb;                                      \
      offB[n] = o ^ (((o >> 9) & 1) << 5);                                  \
    }                                                                       \
  }

#define GEMM_LOOP(ABASE, LDA, BBASE, LDB, S0, S1)                           \
  do {                                                                      \
    const int nt = (S1) - (S0);                                             \
    const char *pA0, *pA1, *pB0;                                            \
    {                                                                       \
      const size_t srow = wave * 16 + (lane >> 2);                          \
      const int scb = ((lane & 3) * 16) ^ (((lane >> 5) & 1) << 5);         \
      pA0 = (const char*)(ABASE) + srow * ((size_t)(LDA) * 2) +             \
            (size_t)(S0) * 64 + scb;                                        \
      pA1 = pA0 + (size_t)128 * ((size_t)(LDA) * 2);                        \
      pB0 = (const char*)(BBASE) + srow * ((size_t)(LDB) * 2) +             \
            (size_t)(S0) * 64 + scb;                                        \
    }                                                                       \
    char* ldsA = (char*)&As[0][0];                                          \
    char* ldsB = (char*)&Bs[0][0];                                          \
    const int wofs = wave * 1024;                                           \
    gload_lds16(pA0, ldsA + wofs);                                          \
    gload_lds16(pA1, ldsA + 8192 + wofs);                                   \
    gload_lds16(pB0, ldsB + wofs);                                          \
    pA0 += 64; pA1 += 64; pB0 += 64;                                        \
    if (nt > 1) {                                                           \
      gload_lds16(pA0, ldsA + 16384 + wofs);                                \
      gload_lds16(pA1, ldsA + 16384 + 8192 + wofs);                         \
      gload_lds16(pB0, ldsB + 8192 + wofs);                                 \
      pA0 += 64; pA1 += 64; pB0 += 64;                                      \
      asm volatile("s_waitcnt vmcnt(3)" ::: "memory");                      \
    } else {                                                                \
      asm volatile("s_waitcnt vmcnt(0)" ::: "memory");                      \
    }                                                                       \
    asm volatile("s_barrier" ::: "memory");                                 \
    int rb = 0;                                                             \
    for (int s = 0; s < nt; ++s) {                                          \
      const int bofsA = rb * 16384, bofsB = rb * 8192;                      \
      bf16x8 a[4], b[4];                                                    \
      _Pragma("unroll")                                                     \
      for (int m = 0; m < 4; ++m)                                           \
        a[m] = *(const bf16x8*)(ldsA + bofsA + offA[m]);                    \
      _Pragma("unroll")                                                     \
      for (int n = 0; n < 4; ++n)                                           \
        b[n] = *(const bf16x8*)(ldsB + bofsB + offB[n]);                    \
      if (s + 2 < nt) {                                                     \
        const int wb = (rb >= 1) ? rb - 1 : 2;                              \
        gload_lds16(pA0, ldsA + wb * 16384 + wofs);                         \
        gload_lds16(pA1, ldsA + wb * 16384 + 8192 + wofs);                  \
        gload_lds16(pB0, ldsB + wb * 8192 + wofs);                          \
        pA0 += 64; pA1 += 64; pB0 += 64;                                    \
        asm volatile("s_waitcnt lgkmcnt(0)" ::: "memory");                  \
        asm volatile("s_waitcnt vmcnt(3)" ::: "memory");                    \
      } else if (s + 1 < nt) {                                              \
        asm volatile("s_waitcnt lgkmcnt(0)" ::: "memory");                  \
        asm volatile("s_waitcnt vmcnt(0)" ::: "memory");                    \
      } else {                                                              \
        asm volatile("s_waitcnt lgkmcnt(0)" ::: "memory");                  \
      }                                                                     \
      asm volatile("s_barrier" ::: "memory");                               \
      __builtin_amdgcn_s_setprio(1);                                        \
      _Pragma("unroll")                                                     \
      for (int m = 0; m < 4; ++m)                                           \
        _Pragma("unroll")                                                   \
        for (int n = 0; n < 4; ++n)                                         \
          acc[m][n] = __builtin_amdgcn_mfma_f32_16x16x32_bf16(              \
              a[m], b[n], acc[m][n], 0, 0, 0);                              \
      __builtin_amdgcn_s_setprio(0);                                        \
      rb = (rb == 2) ? 0 : rb + 1;                                          \
    }                                                                       \
  } while (0)

// ---- QKV: C[4096,3072] = xb @ Wcat^T; Q,K row-major; V transposed ----
__global__ __launch_bounds__(512, 4) void gemm_qkv(const unsigned short* __restrict__ X,
                                                   const unsigned short* __restrict__ W,
                                                   unsigned short* __restrict__ Qb,
                                                   unsigned short* __restrict__ Kb,
                                                   unsigned short* __restrict__ Vt) {
  GEMM_PRE();
  const int brow = blockIdx.y * 256, bcol = blockIdx.x * 128;
  GEMM_LOOP(X + (size_t)brow * DDIM, DDIM, W + (size_t)bcol * DDIM, DDIM, 0, 32);
  const int region = bcol >> 10;  // 0=Q 1=K 2=V
  const int lcol = bcol & 1023;
  const int c0 = wc + (lane & 15);
  const int r0 = wr + ((lane >> 4) << 2);
  if (region < 2) {
    unsigned short* dst = (region == 0) ? Qb : Kb;
#pragma unroll
    for (int m = 0; m < 4; ++m) {
      const int r = brow + r0 + m * 16;
#pragma unroll
      for (int n = 0; n < 4; ++n) {
        const int c = lcol + c0 + n * 16;
#pragma unroll
        for (int j = 0; j < 4; ++j)
          dst[(size_t)(r + j) * DDIM + c] = f2bf(acc[m][n][j]);
      }
    }
  } else {
#pragma unroll
    for (int m = 0; m < 4; ++m) {
      const int r = brow + r0 + m * 16;
#pragma unroll
      for (int n = 0; n < 4; ++n) {
        const int c = lcol + c0 + n * 16;
        ushort4 pk;
        pk.x = f2bf(acc[m][n][0]);
        pk.y = f2bf(acc[m][n][1]);
        pk.z = f2bf(acc[m][n][2]);
        pk.w = f2bf(acc[m][n][3]);
        *reinterpret_cast<ushort4*>(Vt + (size_t)c * SEQQ + r) = pk;
      }
    }
  }
}

// ---- QK^T: S = Qb @ Kb^T, causal tiles (256-row x 128-col) ----
__global__ __launch_bounds__(512, 4) void gemm_qkt(const unsigned short* __restrict__ Qb,
                                                   const unsigned short* __restrict__ Kb,
                                                   unsigned short* __restrict__ S) {
  const int bi = blockIdx.y, bj = blockIdx.x;
  if (bj > 2 * bi + 1) return;  // tile fully above the diagonal
  GEMM_PRE();
  const int brow = bi * 256, bcol = bj * 128;
  GEMM_LOOP(Qb + (size_t)brow * DDIM, DDIM, Kb + (size_t)bcol * DDIM, DDIM, 0, 32);
  const int c0 = wc + (lane & 15);
  const int r0 = wr + ((lane >> 4) << 2);
#pragma unroll
  for (int m = 0; m < 4; ++m) {
    const int r = brow + r0 + m * 16;
#pragma unroll
    for (int n = 0; n < 4; ++n) {
      const int c = bcol + c0 + n * 16;
#pragma unroll
      for (int j = 0; j < 4; ++j) {
        unsigned short o = (c > r + j) ? (unsigned short)0xFF80  // -inf bf16
                                       : f2bf(acc[m][n][j]);
        S[(size_t)(r + j) * SEQQ + c] = o;
      }
    }
  }
}

// ---- row softmax over causal prefix (256-padded), in place ----
__global__ __launch_bounds__(256) void softmax_causal(unsigned short* __restrict__ S) {
  const int row = blockIdx.x;
  const int L = ((row >> 8) + 1) << 8;  // 256-padded: matches PV K-extent
  unsigned short* Srow = S + (size_t)row * SEQQ;
  __shared__ float red[4];
  const int tid = threadIdx.x;
  const int lane = tid & 63, wave = tid >> 6;

  float x[16];
  bool have[2];
  float m = -3.0e38f;
#pragma unroll
  for (int it = 0; it < 2; ++it) {
    const int j = tid * 8 + it * 2048;
    have[it] = (j < L);
    if (have[it]) {
      const uint4 v = *reinterpret_cast<const uint4*>(Srow + j);
      const unsigned u[4] = {v.x, v.y, v.z, v.w};
#pragma unroll
      for (int q = 0; q < 4; ++q) {
        x[it * 8 + q * 2] = __builtin_bit_cast(float, u[q] << 16);
        x[it * 8 + q * 2 + 1] = __builtin_bit_cast(float, u[q] & 0xFFFF0000u);
      }
#pragma unroll
      for (int q = 0; q < 8; ++q) m = fmaxf(m, x[it * 8 + q]);
    }
  }
#pragma unroll
  for (int o = 32; o; o >>= 1) m = fmaxf(m, __shfl_xor(m, o));
  if (lane == 0) red[wave] = m;
  __syncthreads();
  m = fmaxf(fmaxf(red[0], red[1]), fmaxf(red[2], red[3]));
  __syncthreads();

  float sum = 0.f;
#pragma unroll
  for (int it = 0; it < 2; ++it)
    if (have[it]) {
#pragma unroll
      for (int q = 0; q < 8; ++q) {
        x[it * 8 + q] = __expf(x[it * 8 + q] - m);  // exp(-inf)=0 for masked
        sum += x[it * 8 + q];
      }
    }
#pragma unroll
  for (int o = 32; o; o >>= 1) sum += __shfl_xor(sum, o);
  if (lane == 0) red[wave] = sum;
  __syncthreads();
  sum = red[0] + red[1] + red[2] + red[3];
  const float inv = 1.0f / sum;

#pragma unroll
  for (int it = 0; it < 2; ++it)
    if (have[it]) {
      const int j = tid * 8 + it * 2048;
      unsigned u[4];
#pragma unroll
      for (int q = 0; q < 4; ++q) {
        u[q] = (unsigned)f2bf(x[it * 8 + q * 2] * inv) |
               ((unsigned)f2bf(x[it * 8 + q * 2 + 1] * inv) << 16);
      }
      *reinterpret_cast<uint4*>(Srow + j) = make_uint4(u[0], u[1], u[2], u[3]);
    }
}

// ---- split-K helpers for PV (256-row blocks bi=0..15) ----
__device__ __forceinline__ int pv_nc(int bi) { return (bi >> 2) + 1; }
__device__ __forceinline__ int pv_rcbase(int bi) {
  const int g = bi >> 2, r = bi & 3;
  return 2 * g * (g - 1) + r * g;
}

// ---- PV: out/partials = P @ Vt^T, causal K-range, split-K ----
__global__ __launch_bounds__(512, 4) void gemm_pv_split(const unsigned short* __restrict__ P,
                                                        const unsigned short* __restrict__ Vt,
                                                        float* __restrict__ O,
                                                        float* __restrict__ part) {
  const int bj = blockIdx.x, bi = blockIdx.y, ck = blockIdx.z;
  const int nc = pv_nc(bi);
  if (ck >= nc) return;
  const int kt = (bi + 1) * 8;                  // K-tiles of 32 elems
  const int W = (kt + nc - 1) / nc;
  const int s0 = ck * W;
  const int s1 = min(s0 + W, kt);
  if (s0 >= s1) return;

  GEMM_PRE();
  const int brow = bi * 256, bcol = bj * 128;
  GEMM_LOOP(P + (size_t)brow * SEQQ, SEQQ, Vt + (size_t)bcol * SEQQ, SEQQ, s0, s1);
  const int c0 = wc + (lane & 15);
  const int r0 = wr + ((lane >> 4) << 2);
  if (ck == 0) {
#pragma unroll
    for (int m = 0; m < 4; ++m) {
      const int r = brow + r0 + m * 16;
#pragma unroll
      for (int n = 0; n < 4; ++n) {
        const int c = bcol + c0 + n * 16;
#pragma unroll
        for (int j = 0; j < 4; ++j)
          O[(size_t)(r + j) * DDIM + c] = acc[m][n][j];
      }
    }
  } else {
    float* tile = part + ((size_t)(pv_rcbase(bi) + (ck - 1)) * 8 + bj) * 32768;
#pragma unroll
    for (int m = 0; m < 4; ++m) {
      const int lr = r0 + m * 16;
#pragma unroll
      for (int n = 0; n < 4; ++n) {
        const int lc = c0 + n * 16;
#pragma unroll
        for (int j = 0; j < 4; ++j)
          tile[(lr + j) * 128 + lc] = acc[m][n][j];
      }
    }
  }
}

// ---- add partial tiles into out rows >= 1024 ----
__global__ __launch_bounds__(256) void reduce_pv(float* __restrict__ O,
                                                 const float* __restrict__ part) {
  const int idx = blockIdx.x * 256 + threadIdx.x;   // one float4 per thread
  const int r = 1024 + (idx >> 8);                  // 256 float4s per row
  const int cc = (idx & 255) * 4;
  const int bi = r >> 8;
  const int nparts = bi >> 2;                       // nc-1
  const int rcb = pv_rcbase(bi);
  const int bj = cc >> 7;                           // 128-col tiles
  const int lr = r & 255, lc = cc & 127;
  float4 acc = *reinterpret_cast<float4*>(O + (size_t)r * DDIM + cc);
  for (int k = 0; k < nparts; ++k) {
    const float4 p = *reinterpret_cast<const float4*>(
        part + ((size_t)(rcb + k) * 8 + bj) * 32768 + lr * 128 + lc);
    acc.x += p.x; acc.y += p.y; acc.z += p.z; acc.w += p.w;
  }
  *reinterpret_cast<float4*>(O + (size_t)r * DDIM + cc) = acc;
}

extern "C" void kernel_launch(void* const* d_in, const int* in_sizes, int n_in,
                              void* d_out, int out_size, void* d_ws, size_t ws_size,
                              hipStream_t stream) {
  (void)in_sizes; (void)n_in; (void)out_size; (void)ws_size;
  const float* x = (const float*)d_in[0];
  const float* Wq = (const float*)d_in[1];
  const float* Wk = (const float*)d_in[2];
  const float* Wv = (const float*)d_in[3];
  float* out = (float*)d_out;

  char* ws = (char*)d_ws;
  unsigned short* xb   = (unsigned short*)(ws);                        //  8 MB [4096,1024]
  unsigned short* Wcat = (unsigned short*)(ws + ((size_t)8 << 20));    //  6 MB [3072,1024]
  unsigned short* Qb   = (unsigned short*)(ws + ((size_t)14 << 20));   //  8 MB [4096,1024]
  unsigned short* Kb   = (unsigned short*)(ws + ((size_t)22 << 20));   //  8 MB [4096,1024]
  unsigned short* Vt   = (unsigned short*)(ws + ((size_t)30 << 20));   //  8 MB [1024,4096]
  unsigned short* S    = (unsigned short*)(ws + ((size_t)38 << 20));   // 32 MB [4096,4096]
  float* part = (float*)ws;  // 24 MB fp32 partials; reuses dead xb/Wcat/Qb/Kb region

  cvt_all<<<7168, 256, 0, stream>>>(x, Wq, Wk, Wv, xb, Wcat);
  gemm_qkv<<<dim3(24, 16), 512, 0, stream>>>(xb, Wcat, Qb, Kb, Vt);
  gemm_qkt<<<dim3(32, 16), 512, 0, stream>>>(Qb, Kb, S);
  softmax_causal<<<SEQQ, 256, 0, stream>>>(S);
  gemm_pv_split<<<dim3(8, 16, 4), 512, 0, stream>>>(S, Vt, out, part);
  reduce_pv<<<3072, 256, 0, stream>>>(out, part);
}

// Round 10
// 131.269 us; speedup vs baseline: 1.0487x; 1.0487x over previous
//
#include <hip/hip_runtime.h>
#include <hip/hip_bf16.h>
#include <cstdint>
#include <cstddef>

// SelfAttentionV2: x[4096,1024] fp32; Wq/Wk/Wv [1024,1024] fp32.
// out = softmax(causal((x Wq^T)(x Wk^T)^T / 32)) @ (x Wv^T), fp32 out.
//
// GEMM structure (R8 base + register pipeline): 256x256 tile, 8 waves, per-wave
// out 128x64 (acc[8][4]), BK=32, 3 LDS K-tile ring buffers (96KB). One barrier
// per K-tile; ds_reads for tile s+1 issued AFTER barrier(s) into the alternate
// fragment set while MFMA(tile s) runs on the current set (reads in flight
// overlap MFMA — no waitcnt between them). Step s:
//   { stage tile s+2 into buf(s+2)%3 -> lgkmcnt(0) [operands for THIS MFMA
//     ready + drains reads of buf(s+1) before its eventual re-stage]
//     -> sched_barrier(0) [rule 18: MFMA must not hoist above the drain]
//     -> vmcnt(4) [buf s+1 landed] -> s_barrier
//     -> ds_read buf(s+1) -> nextRegs (not waited)
//     -> setprio(1) 32 MFMA(curRegs) setprio(0) }
// Hazard proof: reads of buf X (issued at step X-1) drain at lgkmcnt(0) of
// step X, before barrier(X); the stage overwriting buf X issues at step X+1
// after barrier(X). Even/odd reg sets statically named (rule 20).
// LDS rows 64B; XOR swizzle byte ^= ((byte>>9)&1)<<5 on global SOURCE at
// stage (global_load_lds writes linearly) and on ds_read addrs.

#define SEQQ 4096
#define DDIM 1024

typedef __bf16 bf16x8 __attribute__((ext_vector_type(8)));
typedef float f32x4 __attribute__((ext_vector_type(4)));

__device__ __forceinline__ unsigned short f2bf(float f) {
  unsigned int u = __builtin_bit_cast(unsigned int, f);
  unsigned int r = u + 0x7FFFu + ((u >> 16) & 1u);  // RNE; -inf stays -inf
  return (unsigned short)(r >> 16);
}

__device__ __forceinline__ void gload_lds16(const void* g, void* lds) {
  __builtin_amdgcn_global_load_lds(
      (__attribute__((address_space(1))) void*)(uintptr_t)g,
      (__attribute__((address_space(3))) void*)(uintptr_t)lds, 16, 0, 0);
}

// ---- fused fp32 -> bf16 conversion (x, Wq*1/32, Wk, Wv) ----
__global__ __launch_bounds__(256) void cvt_all(const float* __restrict__ x,
                                               const float* __restrict__ Wq,
                                               const float* __restrict__ Wk,
                                               const float* __restrict__ Wv,
                                               unsigned short* __restrict__ xb,
                                               unsigned short* __restrict__ Wcat) {
  int b = blockIdx.x;
  const float* src;
  unsigned short* dst;
  float scale = 1.0f;
  if (b < 4096) {
    src = x; dst = xb;
  } else if (b < 5120) {
    src = Wq; dst = Wcat; scale = 0.03125f; b -= 4096;
  } else if (b < 6144) {
    src = Wk; dst = Wcat + (1u << 20); b -= 5120;
  } else {
    src = Wv; dst = Wcat + (2u << 20); b -= 6144;
  }
  const int i = (b * 256 + threadIdx.x) * 4;
  const float4 v = *reinterpret_cast<const float4*>(src + i);
  ushort4 o;
  o.x = f2bf(v.x * scale);
  o.y = f2bf(v.y * scale);
  o.z = f2bf(v.z * scale);
  o.w = f2bf(v.w * scale);
  *reinterpret_cast<ushort4*>(dst + i) = o;
}

// ---- 256x256 GEMM core: LDS [3 buf][256 r][32 c] bf16 per operand ----
#define GEMM_PRE()                                                          \
  __shared__ unsigned short As[3][8192] __attribute__((aligned(16)));       \
  __shared__ unsigned short Bs[3][8192] __attribute__((aligned(16)));       \
  const int tid = threadIdx.x;                                              \
  const int wave = tid >> 6, lane = tid & 63;                               \
  const int wr = (wave >> 2) * 128, wc = (wave & 3) * 64;                   \
  f32x4 acc[8][4] = {};                                                     \
  int offA[8], offB[4];                                                     \
  {                                                                         \
    const int cb = (lane >> 4) * 16;                                        \
    const int rA = wr + (lane & 15);                                        \
    _Pragma("unroll")                                                       \
    for (int m = 0; m < 8; ++m) {                                           \
      int o = (rA + m * 16) * 64 + cb;                                      \
      offA[m] = o ^ (((o >> 9) & 1) << 5);                                  \
    }                                                                       \
    const int rB = wc + (lane & 15);                                        \
    _Pragma("unroll")                                                       \
    for (int n = 0; n < 4; ++n) {                                           \
      int o = (rB + n * 16) * 64 + cb;                                      \
      offB[n] = o ^ (((o >> 9) & 1) << 5);                                  \
    }                                                                       \
  }

// One K-tile step. AC/BC: fragments for THIS tile's MFMA (already loaded).
// AN/BN: fragment set to fill with NEXT tile's operands.
#define GEMM_STEP(AC, BC, AN, BN, s)                                        \
  {                                                                         \
    if ((s) + 2 < nt) {                                                     \
      const int wb = (rb >= 1) ? rb - 1 : 2;                                \
      const int wofs2 = wb * 16384 + wofs;                                  \
      gload_lds16(pA0, ldsA + wofs2);                                       \
      gload_lds16(pA1, ldsA + wofs2 + 8192);                                \
      gload_lds16(pB0, ldsB + wofs2);                                       \
      gload_lds16(pB1, ldsB + wofs2 + 8192);                                \
      pA0 += 64; pA1 += 64; pB0 += 64; pB1 += 64;                           \
      asm volatile("s_waitcnt lgkmcnt(0)" ::: "memory");                    \
      __builtin_amdgcn_sched_barrier(0);                                    \
      asm volatile("s_waitcnt vmcnt(4)" ::: "memory");                      \
    } else if ((s) + 1 < nt) {                                              \
      asm volatile("s_waitcnt lgkmcnt(0)" ::: "memory");                    \
      __builtin_amdgcn_sched_barrier(0);                                    \
      asm volatile("s_waitcnt vmcnt(0)" ::: "memory");                      \
    } else {                                                                \
      asm volatile("s_waitcnt lgkmcnt(0)" ::: "memory");                    \
      __builtin_amdgcn_sched_barrier(0);                                    \
    }                                                                       \
    asm volatile("s_barrier" ::: "memory");                                 \
    if ((s) + 1 < nt) {                                                     \
      const int rbn = (rb == 2) ? 0 : rb + 1;                               \
      const int nofs = rbn * 16384;                                         \
      _Pragma("unroll")                                                     \
      for (int m = 0; m < 8; ++m)                                           \
        AN[m] = *(const bf16x8*)(ldsA + nofs + offA[m]);                    \
      _Pragma("unroll")                                                     \
      for (int n = 0; n < 4; ++n)                                           \
        BN[n] = *(const bf16x8*)(ldsB + nofs + offB[n]);                    \
    }                                                                       \
    __builtin_amdgcn_s_setprio(1);                                          \
    _Pragma("unroll")                                                       \
    for (int m = 0; m < 8; ++m)                                             \
      _Pragma("unroll")                                                     \
      for (int n = 0; n < 4; ++n)                                           \
        acc[m][n] = __builtin_amdgcn_mfma_f32_16x16x32_bf16(                \
            AC[m], BC[n], acc[m][n], 0, 0, 0);                              \
    __builtin_amdgcn_s_setprio(0);                                          \
    rb = (rb == 2) ? 0 : rb + 1;                                            \
  }

#define GEMM_LOOP(ABASE, LDA, BBASE, LDB, S0, S1)                           \
  do {                                                                      \
    const int nt = (S1) - (S0);                                             \
    const char *pA0, *pA1, *pB0, *pB1;                                      \
    {                                                                       \
      const size_t srow = wave * 16 + (lane >> 2);                          \
      const int scb = ((lane & 3) * 16) ^ (((lane >> 5) & 1) << 5);         \
      pA0 = (const char*)(ABASE) + srow * ((size_t)(LDA) * 2) +             \
            (size_t)(S0) * 64 + scb;                                        \
      pA1 = pA0 + (size_t)128 * ((size_t)(LDA) * 2);                        \
      pB0 = (const char*)(BBASE) + srow * ((size_t)(LDB) * 2) +             \
            (size_t)(S0) * 64 + scb;                                        \
      pB1 = pB0 + (size_t)128 * ((size_t)(LDB) * 2);                        \
    }                                                                       \
    char* ldsA = (char*)&As[0][0];                                          \
    char* ldsB = (char*)&Bs[0][0];                                          \
    const int wofs = wave * 1024;                                           \
    gload_lds16(pA0, ldsA + wofs);                                          \
    gload_lds16(pA1, ldsA + 8192 + wofs);                                   \
    gload_lds16(pB0, ldsB + wofs);                                          \
    gload_lds16(pB1, ldsB + 8192 + wofs);                                   \
    pA0 += 64; pA1 += 64; pB0 += 64; pB1 += 64;                             \
    if (nt > 1) {                                                           \
      gload_lds16(pA0, ldsA + 16384 + wofs);                                \
      gload_lds16(pA1, ldsA + 16384 + 8192 + wofs);                         \
      gload_lds16(pB0, ldsB + 16384 + wofs);                                \
      gload_lds16(pB1, ldsB + 16384 + 8192 + wofs);                         \
      pA0 += 64; pA1 += 64; pB0 += 64; pB1 += 64;                           \
      asm volatile("s_waitcnt vmcnt(4)" ::: "memory");                      \
    } else {                                                                \
      asm volatile("s_waitcnt vmcnt(0)" ::: "memory");                      \
    }                                                                       \
    asm volatile("s_barrier" ::: "memory");                                 \
    bf16x8 aE[8], bE[4], aO[8], bO[4];                                      \
    _Pragma("unroll")                                                       \
    for (int m = 0; m < 8; ++m) aE[m] = *(const bf16x8*)(ldsA + offA[m]);   \
    _Pragma("unroll")                                                       \
    for (int n = 0; n < 4; ++n) bE[n] = *(const bf16x8*)(ldsB + offB[n]);   \
    int rb = 0;                                                             \
    int s = 0;                                                              \
    for (; s + 1 < nt; s += 2) {                                            \
      GEMM_STEP(aE, bE, aO, bO, s);                                         \
      GEMM_STEP(aO, bO, aE, bE, s + 1);                                     \
    }                                                                       \
    if (s < nt) GEMM_STEP(aE, bE, aO, bO, s);                               \
  } while (0)

// ---- QKV: C[4096,3072] = xb @ Wcat^T; Q,K row-major; V transposed ----
__global__ __launch_bounds__(512, 1) void gemm_qkv(const unsigned short* __restrict__ X,
                                                   const unsigned short* __restrict__ W,
                                                   unsigned short* __restrict__ Qb,
                                                   unsigned short* __restrict__ Kb,
                                                   unsigned short* __restrict__ Vt) {
  GEMM_PRE();
  const int brow = blockIdx.y * 256, bcol = blockIdx.x * 256;
  GEMM_LOOP(X + (size_t)brow * DDIM, DDIM, W + (size_t)bcol * DDIM, DDIM, 0, 32);
  const int region = bcol >> 10;  // 0=Q 1=K 2=V
  const int lcol = bcol & 1023;
  const int c0 = wc + (lane & 15);
  const int r0 = wr + ((lane >> 4) << 2);
  if (region < 2) {
    unsigned short* dst = (region == 0) ? Qb : Kb;
#pragma unroll
    for (int m = 0; m < 8; ++m) {
      const int r = brow + r0 + m * 16;
#pragma unroll
      for (int n = 0; n < 4; ++n) {
        const int c = lcol + c0 + n * 16;
#pragma unroll
        for (int j = 0; j < 4; ++j)
          dst[(size_t)(r + j) * DDIM + c] = f2bf(acc[m][n][j]);
      }
    }
  } else {
#pragma unroll
    for (int m = 0; m < 8; ++m) {
      const int r = brow + r0 + m * 16;
#pragma unroll
      for (int n = 0; n < 4; ++n) {
        const int c = lcol + c0 + n * 16;
        ushort4 pk;
        pk.x = f2bf(acc[m][n][0]);
        pk.y = f2bf(acc[m][n][1]);
        pk.z = f2bf(acc[m][n][2]);
        pk.w = f2bf(acc[m][n][3]);
        *reinterpret_cast<ushort4*>(Vt + (size_t)c * SEQQ + r) = pk;
      }
    }
  }
}

// ---- QK^T: S = Qb @ Kb^T, lower-triangle 256-tiles, causal mask ----
__global__ __launch_bounds__(512, 1) void gemm_qkt(const unsigned short* __restrict__ Qb,
                                                   const unsigned short* __restrict__ Kb,
                                                   unsigned short* __restrict__ S) {
  const int bi = blockIdx.y, bj = blockIdx.x;
  if (bj > bi) return;
  GEMM_PRE();
  const int brow = bi * 256, bcol = bj * 256;
  GEMM_LOOP(Qb + (size_t)brow * DDIM, DDIM, Kb + (size_t)bcol * DDIM, DDIM, 0, 32);
  const int c0 = wc + (lane & 15);
  const int r0 = wr + ((lane >> 4) << 2);
#pragma unroll
  for (int m = 0; m < 8; ++m) {
    const int r = brow + r0 + m * 16;
#pragma unroll
    for (int n = 0; n < 4; ++n) {
      const int c = bcol + c0 + n * 16;
#pragma unroll
      for (int j = 0; j < 4; ++j) {
        unsigned short o = (c > r + j) ? (unsigned short)0xFF80  // -inf bf16
                                       : f2bf(acc[m][n][j]);
        S[(size_t)(r + j) * SEQQ + c] = o;
      }
    }
  }
}

// ---- row softmax over causal prefix (256-padded), in place ----
__global__ __launch_bounds__(256) void softmax_causal(unsigned short* __restrict__ S) {
  const int row = blockIdx.x;
  const int L = ((row >> 8) + 1) << 8;  // 256-padded: matches PV K-extent
  unsigned short* Srow = S + (size_t)row * SEQQ;
  __shared__ float red[4];
  const int tid = threadIdx.x;
  const int lane = tid & 63, wave = tid >> 6;

  float x[16];
  bool have[2];
  float m = -3.0e38f;
#pragma unroll
  for (int it = 0; it < 2; ++it) {
    const int j = tid * 8 + it * 2048;
    have[it] = (j < L);
    if (have[it]) {
      const uint4 v = *reinterpret_cast<const uint4*>(Srow + j);
      const unsigned u[4] = {v.x, v.y, v.z, v.w};
#pragma unroll
      for (int q = 0; q < 4; ++q) {
        x[it * 8 + q * 2] = __builtin_bit_cast(float, u[q] << 16);
        x[it * 8 + q * 2 + 1] = __builtin_bit_cast(float, u[q] & 0xFFFF0000u);
      }
#pragma unroll
      for (int q = 0; q < 8; ++q) m = fmaxf(m, x[it * 8 + q]);
    }
  }
#pragma unroll
  for (int o = 32; o; o >>= 1) m = fmaxf(m, __shfl_xor(m, o));
  if (lane == 0) red[wave] = m;
  __syncthreads();
  m = fmaxf(fmaxf(red[0], red[1]), fmaxf(red[2], red[3]));
  __syncthreads();

  float sum = 0.f;
#pragma unroll
  for (int it = 0; it < 2; ++it)
    if (have[it]) {
#pragma unroll
      for (int q = 0; q < 8; ++q) {
        x[it * 8 + q] = __expf(x[it * 8 + q] - m);  // exp(-inf)=0 for masked
        sum += x[it * 8 + q];
      }
    }
#pragma unroll
  for (int o = 32; o; o >>= 1) sum += __shfl_xor(sum, o);
  if (lane == 0) red[wave] = sum;
  __syncthreads();
  sum = red[0] + red[1] + red[2] + red[3];
  const float inv = 1.0f / sum;

#pragma unroll
  for (int it = 0; it < 2; ++it)
    if (have[it]) {
      const int j = tid * 8 + it * 2048;
      unsigned u[4];
#pragma unroll
      for (int q = 0; q < 4; ++q) {
        u[q] = (unsigned)f2bf(x[it * 8 + q * 2] * inv) |
               ((unsigned)f2bf(x[it * 8 + q * 2 + 1] * inv) << 16);
      }
      *reinterpret_cast<uint4*>(Srow + j) = make_uint4(u[0], u[1], u[2], u[3]);
    }
}

// ---- split-K helpers for PV (256-row blocks bi=0..15) ----
__device__ __forceinline__ int pv_nc(int bi) { return (bi >> 2) + 1; }
__device__ __forceinline__ int pv_rcbase(int bi) {
  const int g = bi >> 2, r = bi & 3;
  return 2 * g * (g - 1) + r * g;
}

// ---- PV: out/partials = P @ Vt^T, causal K-range, split-K ----
__global__ __launch_bounds__(512, 1) void gemm_pv_split(const unsigned short* __restrict__ P,
                                                        const unsigned short* __restrict__ Vt,
                                                        float* __restrict__ O,
                                                        float* __restrict__ part) {
  const int bj = blockIdx.x, bi = blockIdx.y, ck = blockIdx.z;
  const int nc = pv_nc(bi);
  if (ck >= nc) return;
  const int kt = (bi + 1) * 8;                  // K-tiles of 32 elems
  const int W = (kt + nc - 1) / nc;
  const int s0 = ck * W;
  const int s1 = min(s0 + W, kt);
  if (s0 >= s1) return;

  GEMM_PRE();
  const int brow = bi * 256, bcol = bj * 256;
  GEMM_LOOP(P + (size_t)brow * SEQQ, SEQQ, Vt + (size_t)bcol * SEQQ, SEQQ, s0, s1);
  const int c0 = wc + (lane & 15);
  const int r0 = wr + ((lane >> 4) << 2);
  if (ck == 0) {
#pragma unroll
    for (int m = 0; m < 8; ++m) {
      const int r = brow + r0 + m * 16;
#pragma unroll
      for (int n = 0; n < 4; ++n) {
        const int c = bcol + c0 + n * 16;
#pragma unroll
        for (int j = 0; j < 4; ++j)
          O[(size_t)(r + j) * DDIM + c] = acc[m][n][j];
      }
    }
  } else {
    float* tile = part + ((size_t)(pv_rcbase(bi) + (ck - 1)) * 4 + bj) * 65536;
#pragma unroll
    for (int m = 0; m < 8; ++m) {
      const int lr = r0 + m * 16;
#pragma unroll
      for (int n = 0; n < 4; ++n) {
        const int lc = c0 + n * 16;
#pragma unroll
        for (int j = 0; j < 4; ++j)
          tile[(lr + j) * 256 + lc] = acc[m][n][j];
      }
    }
  }
}

// ---- add partial tiles into out rows >= 1024 ----
__global__ __launch_bounds__(256) void reduce_pv(float* __restrict__ O,
                                                 const float* __restrict__ part) {
  const int idx = blockIdx.x * 256 + threadIdx.x;   // one float4 per thread
  const int r = 1024 + (idx >> 8);                  // 256 float4s per row
  const int cc = (idx & 255) * 4;
  const int bi = r >> 8;
  const int nparts = bi >> 2;                       // nc-1
  const int rcb = pv_rcbase(bi);
  const int bj = cc >> 8;
  const int lr = r & 255, lc = cc & 255;
  float4 acc = *reinterpret_cast<float4*>(O + (size_t)r * DDIM + cc);
  for (int k = 0; k < nparts; ++k) {
    const float4 p = *reinterpret_cast<const float4*>(
        part + ((size_t)(rcb + k) * 4 + bj) * 65536 + lr * 256 + lc);
    acc.x += p.x; acc.y += p.y; acc.z += p.z; acc.w += p.w;
  }
  *reinterpret_cast<float4*>(O + (size_t)r * DDIM + cc) = acc;
}

extern "C" void kernel_launch(void* const* d_in, const int* in_sizes, int n_in,
                              void* d_out, int out_size, void* d_ws, size_t ws_size,
                              hipStream_t stream) {
  (void)in_sizes; (void)n_in; (void)out_size; (void)ws_size;
  const float* x = (const float*)d_in[0];
  const float* Wq = (const float*)d_in[1];
  const float* Wk = (const float*)d_in[2];
  const float* Wv = (const float*)d_in[3];
  float* out = (float*)d_out;

  char* ws = (char*)d_ws;
  unsigned short* xb   = (unsigned short*)(ws);                        //  8 MB [4096,1024]
  unsigned short* Wcat = (unsigned short*)(ws + ((size_t)8 << 20));    //  6 MB [3072,1024]
  unsigned short* Qb   = (unsigned short*)(ws + ((size_t)14 << 20));   //  8 MB [4096,1024]
  unsigned short* Kb   = (unsigned short*)(ws + ((size_t)22 << 20));   //  8 MB [4096,1024]
  unsigned short* Vt   = (unsigned short*)(ws + ((size_t)30 << 20));   //  8 MB [1024,4096]
  unsigned short* S    = (unsigned short*)(ws + ((size_t)38 << 20));   // 32 MB [4096,4096]
  float* part = (float*)ws;  // 24 MB fp32 partials; reuses dead xb/Wcat/Qb/Kb region

  cvt_all<<<7168, 256, 0, stream>>>(x, Wq, Wk, Wv, xb, Wcat);
  gemm_qkv<<<dim3(12, 16), 512, 0, stream>>>(xb, Wcat, Qb, Kb, Vt);
  gemm_qkt<<<dim3(16, 16), 512, 0, stream>>>(Qb, Kb, S);
  softmax_causal<<<SEQQ, 256, 0, stream>>>(S);
  gemm_pv_split<<<dim3(4, 16, 4), 512, 0, stream>>>(S, Vt, out, part);
  reduce_pv<<<3072, 256, 0, stream>>>(out, part);
}

// Round 11
// 130.567 us; speedup vs baseline: 1.0544x; 1.0054x over previous
//
#include <hip/hip_runtime.h>
#include <hip/hip_bf16.h>
#include <cstdint>
#include <cstddef>

// SelfAttentionV2: x[4096,1024] fp32; Wq/Wk/Wv [1024,1024] fp32.
// out = softmax(causal((x Wq^T)(x Wk^T)^T / 32)) @ (x Wv^T), fp32 out.
//
// GEMM structure (R8 + BK=64): 256x256 tile, 8 waves, per-wave out 128x64
// (acc[8][4]), BK=64, 2 LDS buffers (128KB -> 1 block/CU). Each K-tile is two
// [256][32] bf16 slabs (kk=0,1) per operand — the proven 0-conflict layout.
// ONE barrier + ONE vmcnt per 64-wide K-tile:
//   { 12 ds_read kk0 | issue 8 global_load_lds staging tile t+1 into buf^1
//     -> lgkmcnt(0) -> sched_barrier -> setprio(1) 32 MFMA kk0 setprio(0)
//     -> 12 ds_read kk1 -> lgkmcnt(0) -> sched_barrier
//     -> setprio(1) 32 MFMA kk1 setprio(0)
//     -> vmcnt(0) [stages aged ~2.5k cyc] -> s_barrier }
// Hazard proof: buf^1's old reads (tile t-1, both kk) drained at t-1's final
// lgkmcnt(0) before barrier(t-1); every wave passed barrier(t-1) before any
// wave issues tile t's stages. Entering tile t, buf[t&1] was staged during
// t-1 and validated by vmcnt(0) before barrier(t-1).
// LDS slab rows 64B; XOR swizzle byte ^= ((byte>>9)&1)<<5 on global SOURCE
// at stage (global_load_lds writes linearly) and on ds_read addrs.

#define SEQQ 4096
#define DDIM 1024

typedef __bf16 bf16x8 __attribute__((ext_vector_type(8)));
typedef float f32x4 __attribute__((ext_vector_type(4)));

__device__ __forceinline__ unsigned short f2bf(float f) {
  unsigned int u = __builtin_bit_cast(unsigned int, f);
  unsigned int r = u + 0x7FFFu + ((u >> 16) & 1u);  // RNE; -inf stays -inf
  return (unsigned short)(r >> 16);
}

__device__ __forceinline__ void gload_lds16(const void* g, void* lds) {
  __builtin_amdgcn_global_load_lds(
      (__attribute__((address_space(1))) void*)(uintptr_t)g,
      (__attribute__((address_space(3))) void*)(uintptr_t)lds, 16, 0, 0);
}

// ---- fused fp32 -> bf16 conversion (x, Wq*1/32, Wk, Wv) ----
__global__ __launch_bounds__(256) void cvt_all(const float* __restrict__ x,
                                               const float* __restrict__ Wq,
                                               const float* __restrict__ Wk,
                                               const float* __restrict__ Wv,
                                               unsigned short* __restrict__ xb,
                                               unsigned short* __restrict__ Wcat) {
  int b = blockIdx.x;
  const float* src;
  unsigned short* dst;
  float scale = 1.0f;
  if (b < 4096) {
    src = x; dst = xb;
  } else if (b < 5120) {
    src = Wq; dst = Wcat; scale = 0.03125f; b -= 4096;
  } else if (b < 6144) {
    src = Wk; dst = Wcat + (1u << 20); b -= 5120;
  } else {
    src = Wv; dst = Wcat + (2u << 20); b -= 6144;
  }
  const int i = (b * 256 + threadIdx.x) * 4;
  const float4 v = *reinterpret_cast<const float4*>(src + i);
  ushort4 o;
  o.x = f2bf(v.x * scale);
  o.y = f2bf(v.y * scale);
  o.z = f2bf(v.z * scale);
  o.w = f2bf(v.w * scale);
  *reinterpret_cast<ushort4*>(dst + i) = o;
}

// ---- 256x256 BK=64 GEMM core ----
// Per operand: 2 buffers x 2 slabs x [256 r][32 c] bf16 (slab 16KB, buf 32KB).
#define GEMM_PRE()                                                          \
  __shared__ unsigned short As[2][32768 / 2] __attribute__((aligned(16)));  \
  __shared__ unsigned short Bs[2][32768 / 2] __attribute__((aligned(16)));  \
  const int tid = threadIdx.x;                                              \
  const int wave = tid >> 6, lane = tid & 63;                               \
  const int wr = (wave >> 2) * 128, wc = (wave & 3) * 64;                   \
  f32x4 acc[8][4] = {};                                                     \
  int offA[8], offB[4];                                                     \
  {                                                                         \
    const int cb = (lane >> 4) * 16;                                        \
    const int rA = wr + (lane & 15);                                        \
    _Pragma("unroll")                                                       \
    for (int m = 0; m < 8; ++m) {                                           \
      int o = (rA + m * 16) * 64 + cb;                                      \
      offA[m] = o ^ (((o >> 9) & 1) << 5);                                  \
    }                                                                       \
    const int rB = wc + (lane & 15);                                        \
    _Pragma("unroll")                                                       \
    for (int n = 0; n < 4; ++n) {                                           \
      int o = (rB + n * 16) * 64 + cb;                                      \
      offB[n] = o ^ (((o >> 9) & 1) << 5);                                  \
    }                                                                       \
  }

// Stage one full K-tile (A+B, both slabs) into buffer at byte offset BOFS,
// then advance source pointers by one K-tile (128B).
#define STAGE(BOFS)                                                         \
  {                                                                         \
    gload_lds16(sA00, ldsA + (BOFS) + dC0);                                 \
    gload_lds16(sA01, ldsA + (BOFS) + dC1);                                 \
    gload_lds16(sA10, ldsA + (BOFS) + 16384 + dC0);                         \
    gload_lds16(sA11, ldsA + (BOFS) + 16384 + dC1);                         \
    gload_lds16(sB00, ldsB + (BOFS) + dC0);                                 \
    gload_lds16(sB01, ldsB + (BOFS) + dC1);                                 \
    gload_lds16(sB10, ldsB + (BOFS) + 16384 + dC0);                         \
    gload_lds16(sB11, ldsB + (BOFS) + 16384 + dC1);                         \
    sA00 += 128; sA01 += 128; sA10 += 128; sA11 += 128;                     \
    sB00 += 128; sB01 += 128; sB10 += 128; sB11 += 128;                     \
  }

#define GEMM_LOOP(ABASE, LDA, BBASE, LDB, S0, S1)                           \
  do {                                                                      \
    const int nt = (S1) - (S0);                                             \
    const size_t lda2 = (size_t)(LDA) * 2, ldb2 = (size_t)(LDB) * 2;        \
    const int r0s = wave * 16 + (lane >> 2);                                \
    const int scb = ((lane & 3) * 16) ^ (((lane >> 5) & 1) << 5);           \
    const char* sA00 = (const char*)(ABASE) + (size_t)r0s * lda2 +          \
                       (size_t)(S0) * 128 + scb;                            \
    const char* sA01 = sA00 + 128 * lda2;                                   \
    const char* sA10 = sA00 + 64;                                           \
    const char* sA11 = sA01 + 64;                                           \
    const char* sB00 = (const char*)(BBASE) + (size_t)r0s * ldb2 +          \
                       (size_t)(S0) * 128 + scb;                            \
    const char* sB01 = sB00 + 128 * ldb2;                                   \
    const char* sB10 = sB00 + 64;                                           \
    const char* sB11 = sB01 + 64;                                           \
    char* ldsA = (char*)&As[0][0];                                          \
    char* ldsB = (char*)&Bs[0][0];                                          \
    const int dC0 = wave * 1024, dC1 = (8 + wave) * 1024;                   \
    STAGE(0);                                                               \
    asm volatile("s_waitcnt vmcnt(0)" ::: "memory");                        \
    asm volatile("s_barrier" ::: "memory");                                 \
    for (int s = 0; s < nt; ++s) {                                          \
      const int bofs = (s & 1) * 32768;                                     \
      bf16x8 a[8], b[4];                                                    \
      _Pragma("unroll")                                                     \
      for (int m = 0; m < 8; ++m)                                           \
        a[m] = *(const bf16x8*)(ldsA + bofs + offA[m]);                     \
      _Pragma("unroll")                                                     \
      for (int n = 0; n < 4; ++n)                                           \
        b[n] = *(const bf16x8*)(ldsB + bofs + offB[n]);                     \
      if (s + 1 < nt) STAGE((~s & 1) * 32768);                              \
      asm volatile("s_waitcnt lgkmcnt(0)" ::: "memory");                    \
      __builtin_amdgcn_sched_barrier(0);                                    \
      __builtin_amdgcn_s_setprio(1);                                        \
      _Pragma("unroll")                                                     \
      for (int m = 0; m < 8; ++m)                                           \
        _Pragma("unroll")                                                   \
        for (int n = 0; n < 4; ++n)                                         \
          acc[m][n] = __builtin_amdgcn_mfma_f32_16x16x32_bf16(              \
              a[m], b[n], acc[m][n], 0, 0, 0);                              \
      __builtin_amdgcn_s_setprio(0);                                        \
      bf16x8 a2[8], b2[4];                                                  \
      _Pragma("unroll")                                                     \
      for (int m = 0; m < 8; ++m)                                           \
        a2[m] = *(const bf16x8*)(ldsA + bofs + 16384 + offA[m]);            \
      _Pragma("unroll")                                                     \
      for (int n = 0; n < 4; ++n)                                           \
        b2[n] = *(const bf16x8*)(ldsB + bofs + 16384 + offB[n]);            \
      asm volatile("s_waitcnt lgkmcnt(0)" ::: "memory");                    \
      __builtin_amdgcn_sched_barrier(0);                                    \
      __builtin_amdgcn_s_setprio(1);                                        \
      _Pragma("unroll")                                                     \
      for (int m = 0; m < 8; ++m)                                           \
        _Pragma("unroll")                                                   \
        for (int n = 0; n < 4; ++n)                                         \
          acc[m][n] = __builtin_amdgcn_mfma_f32_16x16x32_bf16(              \
              a2[m], b2[n], acc[m][n], 0, 0, 0);                            \
      __builtin_amdgcn_s_setprio(0);                                        \
      if (s + 1 < nt) {                                                     \
        asm volatile("s_waitcnt vmcnt(0)" ::: "memory");                    \
        asm volatile("s_barrier" ::: "memory");                             \
      }                                                                     \
    }                                                                       \
  } while (0)

// ---- QKV: C[4096,3072] = xb @ Wcat^T; Q,K row-major; V transposed ----
__global__ __launch_bounds__(512, 1) void gemm_qkv(const unsigned short* __restrict__ X,
                                                   const unsigned short* __restrict__ W,
                                                   unsigned short* __restrict__ Qb,
                                                   unsigned short* __restrict__ Kb,
                                                   unsigned short* __restrict__ Vt) {
  GEMM_PRE();
  const int brow = blockIdx.y * 256, bcol = blockIdx.x * 256;
  GEMM_LOOP(X + (size_t)brow * DDIM, DDIM, W + (size_t)bcol * DDIM, DDIM, 0, 16);
  const int region = bcol >> 10;  // 0=Q 1=K 2=V
  const int lcol = bcol & 1023;
  const int c0 = wc + (lane & 15);
  const int r0 = wr + ((lane >> 4) << 2);
  if (region < 2) {
    unsigned short* dst = (region == 0) ? Qb : Kb;
#pragma unroll
    for (int m = 0; m < 8; ++m) {
      const int r = brow + r0 + m * 16;
#pragma unroll
      for (int n = 0; n < 4; ++n) {
        const int c = lcol + c0 + n * 16;
#pragma unroll
        for (int j = 0; j < 4; ++j)
          dst[(size_t)(r + j) * DDIM + c] = f2bf(acc[m][n][j]);
      }
    }
  } else {
#pragma unroll
    for (int m = 0; m < 8; ++m) {
      const int r = brow + r0 + m * 16;
#pragma unroll
      for (int n = 0; n < 4; ++n) {
        const int c = lcol + c0 + n * 16;
        ushort4 pk;
        pk.x = f2bf(acc[m][n][0]);
        pk.y = f2bf(acc[m][n][1]);
        pk.z = f2bf(acc[m][n][2]);
        pk.w = f2bf(acc[m][n][3]);
        *reinterpret_cast<ushort4*>(Vt + (size_t)c * SEQQ + r) = pk;
      }
    }
  }
}

// ---- QK^T: S = Qb @ Kb^T, lower-triangle 256-tiles, causal mask ----
__global__ __launch_bounds__(512, 1) void gemm_qkt(const unsigned short* __restrict__ Qb,
                                                   const unsigned short* __restrict__ Kb,
                                                   unsigned short* __restrict__ S) {
  const int bi = blockIdx.y, bj = blockIdx.x;
  if (bj > bi) return;
  GEMM_PRE();
  const int brow = bi * 256, bcol = bj * 256;
  GEMM_LOOP(Qb + (size_t)brow * DDIM, DDIM, Kb + (size_t)bcol * DDIM, DDIM, 0, 16);
  const int c0 = wc + (lane & 15);
  const int r0 = wr + ((lane >> 4) << 2);
#pragma unroll
  for (int m = 0; m < 8; ++m) {
    const int r = brow + r0 + m * 16;
#pragma unroll
    for (int n = 0; n < 4; ++n) {
      const int c = bcol + c0 + n * 16;
#pragma unroll
      for (int j = 0; j < 4; ++j) {
        unsigned short o = (c > r + j) ? (unsigned short)0xFF80  // -inf bf16
                                       : f2bf(acc[m][n][j]);
        S[(size_t)(r + j) * SEQQ + c] = o;
      }
    }
  }
}

// ---- row softmax over causal prefix (256-padded), in place ----
__global__ __launch_bounds__(256) void softmax_causal(unsigned short* __restrict__ S) {
  const int row = blockIdx.x;
  const int L = ((row >> 8) + 1) << 8;  // 256-padded: matches PV K-extent
  unsigned short* Srow = S + (size_t)row * SEQQ;
  __shared__ float red[4];
  const int tid = threadIdx.x;
  const int lane = tid & 63, wave = tid >> 6;

  float x[16];
  bool have[2];
  float m = -3.0e38f;
#pragma unroll
  for (int it = 0; it < 2; ++it) {
    const int j = tid * 8 + it * 2048;
    have[it] = (j < L);
    if (have[it]) {
      const uint4 v = *reinterpret_cast<const uint4*>(Srow + j);
      const unsigned u[4] = {v.x, v.y, v.z, v.w};
#pragma unroll
      for (int q = 0; q < 4; ++q) {
        x[it * 8 + q * 2] = __builtin_bit_cast(float, u[q] << 16);
        x[it * 8 + q * 2 + 1] = __builtin_bit_cast(float, u[q] & 0xFFFF0000u);
      }
#pragma unroll
      for (int q = 0; q < 8; ++q) m = fmaxf(m, x[it * 8 + q]);
    }
  }
#pragma unroll
  for (int o = 32; o; o >>= 1) m = fmaxf(m, __shfl_xor(m, o));
  if (lane == 0) red[wave] = m;
  __syncthreads();
  m = fmaxf(fmaxf(red[0], red[1]), fmaxf(red[2], red[3]));
  __syncthreads();

  float sum = 0.f;
#pragma unroll
  for (int it = 0; it < 2; ++it)
    if (have[it]) {
#pragma unroll
      for (int q = 0; q < 8; ++q) {
        x[it * 8 + q] = __expf(x[it * 8 + q] - m);  // exp(-inf)=0 for masked
        sum += x[it * 8 + q];
      }
    }
#pragma unroll
  for (int o = 32; o; o >>= 1) sum += __shfl_xor(sum, o);
  if (lane == 0) red[wave] = sum;
  __syncthreads();
  sum = red[0] + red[1] + red[2] + red[3];
  const float inv = 1.0f / sum;

#pragma unroll
  for (int it = 0; it < 2; ++it)
    if (have[it]) {
      const int j = tid * 8 + it * 2048;
      unsigned u[4];
#pragma unroll
      for (int q = 0; q < 4; ++q) {
        u[q] = (unsigned)f2bf(x[it * 8 + q * 2] * inv) |
               ((unsigned)f2bf(x[it * 8 + q * 2 + 1] * inv) << 16);
      }
      *reinterpret_cast<uint4*>(Srow + j) = make_uint4(u[0], u[1], u[2], u[3]);
    }
}

// ---- split-K helpers for PV (256-row blocks bi=0..15) ----
__device__ __forceinline__ int pv_nc(int bi) { return (bi >> 2) + 1; }
__device__ __forceinline__ int pv_rcbase(int bi) {
  const int g = bi >> 2, r = bi & 3;
  return 2 * g * (g - 1) + r * g;
}

// ---- PV: out/partials = P @ Vt^T, causal K-range, split-K ----
__global__ __launch_bounds__(512, 1) void gemm_pv_split(const unsigned short* __restrict__ P,
                                                        const unsigned short* __restrict__ Vt,
                                                        float* __restrict__ O,
                                                        float* __restrict__ part) {
  const int bj = blockIdx.x, bi = blockIdx.y, ck = blockIdx.z;
  const int nc = pv_nc(bi);
  if (ck >= nc) return;
  const int kt = (bi + 1) * 4;                  // K-tiles of 64 elems
  const int W = (kt + nc - 1) / nc;
  const int s0 = ck * W;
  const int s1 = min(s0 + W, kt);
  if (s0 >= s1) return;

  GEMM_PRE();
  const int brow = bi * 256, bcol = bj * 256;
  GEMM_LOOP(P + (size_t)brow * SEQQ, SEQQ, Vt + (size_t)bcol * SEQQ, SEQQ, s0, s1);
  const int c0 = wc + (lane & 15);
  const int r0 = wr + ((lane >> 4) << 2);
  if (ck == 0) {
#pragma unroll
    for (int m = 0; m < 8; ++m) {
      const int r = brow + r0 + m * 16;
#pragma unroll
      for (int n = 0; n < 4; ++n) {
        const int c = bcol + c0 + n * 16;
#pragma unroll
        for (int j = 0; j < 4; ++j)
          O[(size_t)(r + j) * DDIM + c] = acc[m][n][j];
      }
    }
  } else {
    float* tile = part + ((size_t)(pv_rcbase(bi) + (ck - 1)) * 4 + bj) * 65536;
#pragma unroll
    for (int m = 0; m < 8; ++m) {
      const int lr = r0 + m * 16;
#pragma unroll
      for (int n = 0; n < 4; ++n) {
        const int lc = c0 + n * 16;
#pragma unroll
        for (int j = 0; j < 4; ++j)
          tile[(lr + j) * 256 + lc] = acc[m][n][j];
      }
    }
  }
}

// ---- add partial tiles into out rows >= 1024 ----
__global__ __launch_bounds__(256) void reduce_pv(float* __restrict__ O,
                                                 const float* __restrict__ part) {
  const int idx = blockIdx.x * 256 + threadIdx.x;   // one float4 per thread
  const int r = 1024 + (idx >> 8);                  // 256 float4s per row
  const int cc = (idx & 255) * 4;
  const int bi = r >> 8;
  const int nparts = bi >> 2;                       // nc-1
  const int rcb = pv_rcbase(bi);
  const int bj = cc >> 8;
  const int lr = r & 255, lc = cc & 255;
  float4 acc = *reinterpret_cast<float4*>(O + (size_t)r * DDIM + cc);
  for (int k = 0; k < nparts; ++k) {
    const float4 p = *reinterpret_cast<const float4*>(
        part + ((size_t)(rcb + k) * 4 + bj) * 65536 + lr * 256 + lc);
    acc.x += p.x; acc.y += p.y; acc.z += p.z; acc.w += p.w;
  }
  *reinterpret_cast<float4*>(O + (size_t)r * DDIM + cc) = acc;
}

extern "C" void kernel_launch(void* const* d_in, const int* in_sizes, int n_in,
                              void* d_out, int out_size, void* d_ws, size_t ws_size,
                              hipStream_t stream) {
  (void)in_sizes; (void)n_in; (void)out_size; (void)ws_size;
  const float* x = (const float*)d_in[0];
  const float* Wq = (const float*)d_in[1];
  const float* Wk = (const float*)d_in[2];
  const float* Wv = (const float*)d_in[3];
  float* out = (float*)d_out;

  char* ws = (char*)d_ws;
  unsigned short* xb   = (unsigned short*)(ws);                        //  8 MB [4096,1024]
  unsigned short* Wcat = (unsigned short*)(ws + ((size_t)8 << 20));    //  6 MB [3072,1024]
  unsigned short* Qb   = (unsigned short*)(ws + ((size_t)14 << 20));   //  8 MB [4096,1024]
  unsigned short* Kb   = (unsigned short*)(ws + ((size_t)22 << 20));   //  8 MB [4096,1024]
  unsigned short* Vt   = (unsigned short*)(ws + ((size_t)30 << 20));   //  8 MB [1024,4096]
  unsigned short* S    = (unsigned short*)(ws + ((size_t)38 << 20));   // 32 MB [4096,4096]
  float* part = (float*)ws;  // 24 MB fp32 partials; reuses dead xb/Wcat/Qb/Kb region

  cvt_all<<<7168, 256, 0, stream>>>(x, Wq, Wk, Wv, xb, Wcat);
  gemm_qkv<<<dim3(12, 16), 512, 0, stream>>>(xb, Wcat, Qb, Kb, Vt);
  gemm_qkt<<<dim3(16, 16), 512, 0, stream>>>(Qb, Kb, S);
  softmax_causal<<<SEQQ, 256, 0, stream>>>(S);
  gemm_pv_split<<<dim3(4, 16, 4), 512, 0, stream>>>(S, Vt, out, part);
  reduce_pv<<<3072, 256, 0, stream>>>(out, part);
}